// Round 1
// baseline (307.796 us; speedup 1.0000x reference)
//
#include <hip/hip_runtime.h>
#include <stdint.h>

// Ragged-batch MHA: N=11136 tokens, 16 segments (contiguous, batch_ids sorted),
// E=256, H=8, hd=32. Pipeline:
//   K0: segment offsets via binary search (17 values)
//   K1: split-cast x/qkv_w -> hi+lo bf16 (fp32-accurate stage-1), o_w -> bf16
//   K2: qkv = x @ qkv_w^T + b  (3-MFMA split), scatter to Q[h][n][d], K[h][n][d], Vt[h][d][n]
//   K3: flash attention per (q-tile of 16, head), per-row segment masks
//   K4: out = attn @ o_w^T + o_b (fp32 out)

#define N_TOK 11136
#define E 256
#define H 8
#define HD 32

typedef __attribute__((ext_vector_type(8))) __bf16 bf16x8;
typedef __attribute__((ext_vector_type(4))) float f32x4;

__device__ __forceinline__ unsigned short f2bf(float f) {
  unsigned int u = __float_as_uint(f);
  u = (u + 0x7FFFu + ((u >> 16) & 1u)) >> 16;   // RNE
  return (unsigned short)u;
}
__device__ __forceinline__ float bf2f(unsigned short s) {
  return __uint_as_float(((unsigned int)s) << 16);
}
__device__ __forceinline__ bf16x8 ld8(const unsigned short* p) {
  return *(const bf16x8*)p;
}

// ---------------- K0: segment offsets ----------------
__global__ void k_offsets(const int* __restrict__ ids, int* __restrict__ offs) {
  int b = threadIdx.x;
  if (b > 16) return;
  int lo = 0, hi = N_TOK;
  while (lo < hi) { int mid = (lo + hi) >> 1; if (ids[mid] < b) lo = mid + 1; else hi = mid; }
  offs[b] = lo;   // lower_bound(b); offs[0]=0, offs[16]=N
}

// ---------------- K1: split cast ----------------
__global__ void k_split(const float* __restrict__ x, const float* __restrict__ qw,
                        const float* __restrict__ ow,
                        unsigned short* __restrict__ xhi, unsigned short* __restrict__ xlo,
                        unsigned short* __restrict__ whi, unsigned short* __restrict__ wlo,
                        unsigned short* __restrict__ owb) {
  const int NX = N_TOK * E;
  const int NW = 3 * E * E;
  const int NO = E * E;
  int total = NX + NW + NO;
  for (int i = blockIdx.x * blockDim.x + threadIdx.x; i < total; i += gridDim.x * blockDim.x) {
    if (i < NX) {
      float v = x[i];
      unsigned short hh = f2bf(v);
      xhi[i] = hh; xlo[i] = f2bf(v - bf2f(hh));
    } else if (i < NX + NW) {
      int j = i - NX; float v = qw[j];
      unsigned short hh = f2bf(v);
      whi[j] = hh; wlo[j] = f2bf(v - bf2f(hh));
    } else {
      int j = i - NX - NW;
      owb[j] = f2bf(ow[j]);
    }
  }
}

// ---------------- K2: qkv projection (split bf16, 3 MFMAs per k-chunk) ----------------
__global__ __launch_bounds__(256) void k_qkv(
    const unsigned short* __restrict__ xhi, const unsigned short* __restrict__ xlo,
    const unsigned short* __restrict__ whi, const unsigned short* __restrict__ wlo,
    const float* __restrict__ qkv_b,
    unsigned short* __restrict__ Qb, unsigned short* __restrict__ Kb,
    unsigned short* __restrict__ Vt) {
  int tid = threadIdx.x;
  int w = tid >> 6, lane = tid & 63, m = lane & 15, quad = lane >> 4;
  int tok0 = blockIdx.x * 64, col0 = blockIdx.y * 64;
  f32x4 acc[4] = {};
  int arow = tok0 + 16 * w + m;
  const unsigned short* xh = xhi + arow * E;
  const unsigned short* xl = xlo + arow * E;
  for (int kc = 0; kc < 8; ++kc) {
    int ko = kc * 32 + quad * 8;
    bf16x8 ah = ld8(xh + ko), al = ld8(xl + ko);
#pragma unroll
    for (int t = 0; t < 4; ++t) {
      int wrow = col0 + 16 * t + m;
      bf16x8 bh = ld8(whi + wrow * E + ko);
      bf16x8 bl = ld8(wlo + wrow * E + ko);
      acc[t] = __builtin_amdgcn_mfma_f32_16x16x32_bf16(ah, bh, acc[t], 0, 0, 0);
      acc[t] = __builtin_amdgcn_mfma_f32_16x16x32_bf16(ah, bl, acc[t], 0, 0, 0);
      acc[t] = __builtin_amdgcn_mfma_f32_16x16x32_bf16(al, bh, acc[t], 0, 0, 0);
    }
  }
  // epilogue: C layout col=lane&15, row=quad*4+reg. 16-col groups never straddle q/k/v
  // boundaries (all multiples of 32), so the branch is wave-uniform per t.
#pragma unroll
  for (int t = 0; t < 4; ++t) {
    int j = col0 + 16 * t + m;
    int hd = j / 96;
    int rr = j - hd * 96;
    float bias = qkv_b[j];
    if (rr < 64) {
      unsigned short* dst = (rr < 32) ? (Qb + (size_t)hd * N_TOK * HD + rr)
                                      : (Kb + (size_t)hd * N_TOK * HD + (rr - 32));
#pragma unroll
      for (int r = 0; r < 4; ++r) {
        int tok = tok0 + 16 * w + quad * 4 + r;
        dst[(size_t)tok * HD] = f2bf(acc[t][r] + bias);
      }
    } else {
      int d = rr - 64;
      int tokb = tok0 + 16 * w + quad * 4;   // 4 consecutive tokens -> 8B packed store
      ushort4 pk;
      pk.x = f2bf(acc[t][0] + bias); pk.y = f2bf(acc[t][1] + bias);
      pk.z = f2bf(acc[t][2] + bias); pk.w = f2bf(acc[t][3] + bias);
      *(ushort4*)(Vt + (size_t)(hd * HD + d) * N_TOK + tokb) = pk;
    }
  }
}

// ---------------- K3: flash attention, 1 wave per (16-row q-tile, head) ----------------
__global__ __launch_bounds__(64) void k_attn(
    const int* __restrict__ ids, const int* __restrict__ offs,
    const unsigned short* __restrict__ Qb, const unsigned short* __restrict__ Kb,
    const unsigned short* __restrict__ Vt,
    unsigned short* __restrict__ attnb) {
  __shared__ unsigned short ldsP[16 * 40];   // stride 40 elems (80B): 16B-aligned rows, <=2-way banks
  int lane = threadIdx.x;
  int m = lane & 15, quad = lane >> 4;
  int h = blockIdx.y;
  int q0 = blockIdx.x * 16;
  int st[4], en[4];
#pragma unroll
  for (int r = 0; r < 4; ++r) {            // C-layout rows quad*4+r
    int tok = q0 + quad * 4 + r;
    int b = ids[tok];
    st[r] = offs[b]; en[r] = offs[b + 1];
  }
  int kmin = min(min(st[0], st[1]), min(st[2], st[3]));
  int kmax = max(max(en[0], en[1]), max(en[2], en[3]));
  kmin = min(kmin, __shfl_xor(kmin, 16)); kmin = min(kmin, __shfl_xor(kmin, 32));
  kmax = max(kmax, __shfl_xor(kmax, 16)); kmax = max(kmax, __shfl_xor(kmax, 32));

  bf16x8 qf = ld8(Qb + (size_t)(h * N_TOK + q0 + m) * HD + quad * 8);
  f32x4 o0 = {}, o1 = {};
  float mr[4] = {-3e38f, -3e38f, -3e38f, -3e38f};
  float lr[4] = {0.f, 0.f, 0.f, 0.f};
  const float SC = 0.17677669529663687f * 1.4426950408889634f;  // 1/sqrt(32)*log2(e)

  for (int k0 = (kmin & ~31); k0 < kmax; k0 += 32) {   // k0 32-aligned, k0+31 < N
    bf16x8 kf0 = ld8(Kb + (size_t)(h * N_TOK + k0 + m) * HD + quad * 8);
    bf16x8 kf1 = ld8(Kb + (size_t)(h * N_TOK + k0 + 16 + m) * HD + quad * 8);
    f32x4 z = {};
    f32x4 s0 = __builtin_amdgcn_mfma_f32_16x16x32_bf16(qf, kf0, z, 0, 0, 0);
    f32x4 s1 = __builtin_amdgcn_mfma_f32_16x16x32_bf16(qf, kf1, z, 0, 0, 0);
    int j0 = k0 + m, j1 = k0 + 16 + m;
#pragma unroll
    for (int r = 0; r < 4; ++r) {
      bool ok0 = (j0 >= st[r]) && (j0 < en[r]);
      bool ok1 = (j1 >= st[r]) && (j1 < en[r]);
      float v0 = ok0 ? s0[r] * SC : -3e38f;
      float v1 = ok1 ? s1[r] * SC : -3e38f;
      float t = fmaxf(v0, v1);
      t = fmaxf(t, __shfl_xor(t, 1)); t = fmaxf(t, __shfl_xor(t, 2));
      t = fmaxf(t, __shfl_xor(t, 4)); t = fmaxf(t, __shfl_xor(t, 8));
      float mn = fmaxf(mr[r], t);
      float alpha = exp2f(mr[r] - mn);     // 1.0 when both -3e38 (all-masked chunk)
      float p0 = ok0 ? exp2f(v0 - mn) : 0.f;
      float p1 = ok1 ? exp2f(v1 - mn) : 0.f;
      float rs = p0 + p1;
      rs += __shfl_xor(rs, 1); rs += __shfl_xor(rs, 2);
      rs += __shfl_xor(rs, 4); rs += __shfl_xor(rs, 8);
      lr[r] = lr[r] * alpha + rs;
      mr[r] = mn;
      o0[r] *= alpha; o1[r] *= alpha;
      int row = quad * 4 + r;
      ldsP[row * 40 + m] = f2bf(p0);
      ldsP[row * 40 + 16 + m] = f2bf(p1);
    }
    __syncthreads();
    bf16x8 pf = ld8(&ldsP[m * 40 + quad * 8]);     // A-layout read of P
    bf16x8 vf0 = ld8(Vt + (size_t)(h * HD + m) * N_TOK + k0 + quad * 8);
    bf16x8 vf1 = ld8(Vt + (size_t)(h * HD + 16 + m) * N_TOK + k0 + quad * 8);
    o0 = __builtin_amdgcn_mfma_f32_16x16x32_bf16(pf, vf0, o0, 0, 0, 0);
    o1 = __builtin_amdgcn_mfma_f32_16x16x32_bf16(pf, vf1, o1, 0, 0, 0);
    __syncthreads();
  }
#pragma unroll
  for (int r = 0; r < 4; ++r) {
    int tok = q0 + quad * 4 + r;
    float inv = 1.0f / lr[r];   // row always has >=1 valid key (its own segment)
    attnb[(size_t)tok * E + h * HD + m] = f2bf(o0[r] * inv);
    attnb[(size_t)tok * E + h * HD + 16 + m] = f2bf(o1[r] * inv);
  }
}

// ---------------- K4: output projection ----------------
__global__ __launch_bounds__(256) void k_oproj(
    const unsigned short* __restrict__ attnb, const unsigned short* __restrict__ owb,
    const float* __restrict__ ob, float* __restrict__ out) {
  int tid = threadIdx.x;
  int w = tid >> 6, lane = tid & 63, m = lane & 15, quad = lane >> 4;
  int tok0 = blockIdx.x * 64, col0 = blockIdx.y * 64;
  f32x4 acc[4] = {};
  int arow = tok0 + 16 * w + m;
  for (int kc = 0; kc < 8; ++kc) {
    int ko = kc * 32 + quad * 8;
    bf16x8 a = ld8(attnb + (size_t)arow * E + ko);
#pragma unroll
    for (int t = 0; t < 4; ++t) {
      bf16x8 b = ld8(owb + (size_t)(col0 + 16 * t + m) * E + ko);
      acc[t] = __builtin_amdgcn_mfma_f32_16x16x32_bf16(a, b, acc[t], 0, 0, 0);
    }
  }
#pragma unroll
  for (int t = 0; t < 4; ++t) {
    int j = col0 + 16 * t + m;
    float bias = ob[j];
#pragma unroll
    for (int r = 0; r < 4; ++r) {
      int tok = tok0 + 16 * w + quad * 4 + r;
      out[(size_t)tok * E + j] = acc[t][r] + bias;
    }
  }
}

extern "C" void kernel_launch(void* const* d_in, const int* in_sizes, int n_in,
                              void* d_out, int out_size, void* d_ws, size_t ws_size,
                              hipStream_t stream) {
  const float* x   = (const float*)d_in[0];
  const int*   ids = (const int*)d_in[1];
  const float* qw  = (const float*)d_in[2];
  const float* qb  = (const float*)d_in[3];
  const float* ow  = (const float*)d_in[4];
  const float* ob  = (const float*)d_in[5];
  float* out = (float*)d_out;

  char* p = (char*)d_ws;
  auto alloc = [&](size_t bytes) {
    char* r = p;
    p += (bytes + 255) & ~(size_t)255;
    return r;
  };
  int* offs = (int*)alloc(32 * sizeof(int));
  unsigned short* xhi = (unsigned short*)alloc((size_t)N_TOK * E * 2);
  unsigned short* xlo = (unsigned short*)alloc((size_t)N_TOK * E * 2);
  unsigned short* whi = (unsigned short*)alloc((size_t)3 * E * E * 2);
  unsigned short* wlo = (unsigned short*)alloc((size_t)3 * E * E * 2);
  unsigned short* owb = (unsigned short*)alloc((size_t)E * E * 2);
  unsigned short* Qb  = (unsigned short*)alloc((size_t)N_TOK * E * 2);
  unsigned short* Kb  = (unsigned short*)alloc((size_t)N_TOK * E * 2);
  unsigned short* Vt  = (unsigned short*)alloc((size_t)N_TOK * E * 2);
  unsigned short* att = (unsigned short*)alloc((size_t)N_TOK * E * 2);

  k_offsets<<<dim3(1), dim3(64), 0, stream>>>(ids, offs);
  k_split<<<dim3(2048), dim3(256), 0, stream>>>(x, qw, ow, xhi, xlo, whi, wlo, owb);
  k_qkv<<<dim3(N_TOK / 64, 12), dim3(256), 0, stream>>>(xhi, xlo, whi, wlo, qb, Qb, Kb, Vt);
  k_attn<<<dim3(N_TOK / 16, H), dim3(64), 0, stream>>>(ids, offs, Qb, Kb, Vt, att);
  k_oproj<<<dim3(N_TOK / 64, E / 64), dim3(256), 0, stream>>>(att, owb, ob, out);
}

// Round 2
// 249.850 us; speedup vs baseline: 1.2319x; 1.2319x over previous
//
#include <hip/hip_runtime.h>
#include <stdint.h>

// Ragged-batch MHA: N=11136 tokens, 16 segments (contiguous, batch_ids sorted),
// E=256, H=8, hd=32. Pipeline:
//   K0: segment offsets via binary search (17 values)
//   K1: split-cast x/qkv_w -> hi+lo bf16 (fp32-accurate stage-1), o_w -> bf16
//   K2: qkv = x @ qkv_w^T + b  (3-MFMA split), scatter to Q[h][n][d], K[h][n][d], Vt[h][d][n]
//   K3: flash attention, transposed-score formulation (S^T = K Q^T), 4 waves/block
//   K4: out = attn @ o_w^T + o_b (fp32 out)

#define N_TOK 11136
#define E 256
#define H 8
#define HD 32

typedef __attribute__((ext_vector_type(8))) __bf16 bf16x8;
typedef __attribute__((ext_vector_type(4))) float f32x4;

__device__ __forceinline__ unsigned short f2bf(float f) {
  unsigned int u = __float_as_uint(f);
  u = (u + 0x7FFFu + ((u >> 16) & 1u)) >> 16;   // RNE
  return (unsigned short)u;
}
__device__ __forceinline__ float bf2f(unsigned short s) {
  return __uint_as_float(((unsigned int)s) << 16);
}
__device__ __forceinline__ bf16x8 ld8(const unsigned short* p) {
  return *(const bf16x8*)p;
}

// ---------------- K0: segment offsets ----------------
__global__ void k_offsets(const int* __restrict__ ids, int* __restrict__ offs) {
  int b = threadIdx.x;
  if (b > 16) return;
  int lo = 0, hi = N_TOK;
  while (lo < hi) { int mid = (lo + hi) >> 1; if (ids[mid] < b) lo = mid + 1; else hi = mid; }
  offs[b] = lo;   // lower_bound(b); offs[0]=0, offs[16]=N
}

// ---------------- K1: split cast ----------------
__global__ void k_split(const float* __restrict__ x, const float* __restrict__ qw,
                        const float* __restrict__ ow,
                        unsigned short* __restrict__ xhi, unsigned short* __restrict__ xlo,
                        unsigned short* __restrict__ whi, unsigned short* __restrict__ wlo,
                        unsigned short* __restrict__ owb) {
  const int NX = N_TOK * E;
  const int NW = 3 * E * E;
  const int NO = E * E;
  int total = NX + NW + NO;
  for (int i = blockIdx.x * blockDim.x + threadIdx.x; i < total; i += gridDim.x * blockDim.x) {
    if (i < NX) {
      float v = x[i];
      unsigned short hh = f2bf(v);
      xhi[i] = hh; xlo[i] = f2bf(v - bf2f(hh));
    } else if (i < NX + NW) {
      int j = i - NX; float v = qw[j];
      unsigned short hh = f2bf(v);
      whi[j] = hh; wlo[j] = f2bf(v - bf2f(hh));
    } else {
      int j = i - NX - NW;
      owb[j] = f2bf(ow[j]);
    }
  }
}

// ---------------- K2: qkv projection (split bf16, 3 MFMAs per k-chunk) ----------------
__global__ __launch_bounds__(256) void k_qkv(
    const unsigned short* __restrict__ xhi, const unsigned short* __restrict__ xlo,
    const unsigned short* __restrict__ whi, const unsigned short* __restrict__ wlo,
    const float* __restrict__ qkv_b,
    unsigned short* __restrict__ Qb, unsigned short* __restrict__ Kb,
    unsigned short* __restrict__ Vt) {
  int tid = threadIdx.x;
  int w = tid >> 6, lane = tid & 63, m = lane & 15, quad = lane >> 4;
  int tok0 = blockIdx.x * 64, col0 = blockIdx.y * 64;
  f32x4 acc[4] = {};
  int arow = tok0 + 16 * w + m;
  const unsigned short* xh = xhi + arow * E;
  const unsigned short* xl = xlo + arow * E;
  for (int kc = 0; kc < 8; ++kc) {
    int ko = kc * 32 + quad * 8;
    bf16x8 ah = ld8(xh + ko), al = ld8(xl + ko);
#pragma unroll
    for (int t = 0; t < 4; ++t) {
      int wrow = col0 + 16 * t + m;
      bf16x8 bh = ld8(whi + wrow * E + ko);
      bf16x8 bl = ld8(wlo + wrow * E + ko);
      acc[t] = __builtin_amdgcn_mfma_f32_16x16x32_bf16(ah, bh, acc[t], 0, 0, 0);
      acc[t] = __builtin_amdgcn_mfma_f32_16x16x32_bf16(ah, bl, acc[t], 0, 0, 0);
      acc[t] = __builtin_amdgcn_mfma_f32_16x16x32_bf16(al, bh, acc[t], 0, 0, 0);
    }
  }
  // epilogue: C layout col=lane&15, row=quad*4+reg. 16-col groups never straddle q/k/v
  // boundaries (all multiples of 32), so the branch is wave-uniform per t.
#pragma unroll
  for (int t = 0; t < 4; ++t) {
    int j = col0 + 16 * t + m;
    int hd = j / 96;
    int rr = j - hd * 96;
    float bias = qkv_b[j];
    if (rr < 64) {
      unsigned short* dst = (rr < 32) ? (Qb + (size_t)hd * N_TOK * HD + rr)
                                      : (Kb + (size_t)hd * N_TOK * HD + (rr - 32));
#pragma unroll
      for (int r = 0; r < 4; ++r) {
        int tok = tok0 + 16 * w + quad * 4 + r;
        dst[(size_t)tok * HD] = f2bf(acc[t][r] + bias);
      }
    } else {
      int d = rr - 64;
      int tokb = tok0 + 16 * w + quad * 4;   // 4 consecutive tokens -> 8B packed store
      ushort4 pk;
      pk.x = f2bf(acc[t][0] + bias); pk.y = f2bf(acc[t][1] + bias);
      pk.z = f2bf(acc[t][2] + bias); pk.w = f2bf(acc[t][3] + bias);
      *(ushort4*)(Vt + (size_t)(hd * HD + d) * N_TOK + tokb) = pk;
    }
  }
}

// ---------------- K3: flash attention, transposed scores ----------------
// S^T = K·Q^T via mfma(A=K_frag, B=Q_frag): row=key (quad*4+r), col=q (lane&15).
// Each lane owns ONE q-row -> per-lane scalar m/l/alpha, 2-shuffle reductions.
// O^T = V^T·P^T via mfma(A=V_frag, B=P^T_frag): row=d, col=q.
// 4 waves/block, one 16-row q-tile per wave, no __syncthreads (per-wave LDS).
#define PSTRIDE 72
__global__ __launch_bounds__(256) void k_attn(
    const int* __restrict__ ids, const int* __restrict__ offs,
    const unsigned short* __restrict__ Qb, const unsigned short* __restrict__ Kb,
    const unsigned short* __restrict__ Vt,
    unsigned short* __restrict__ attnb) {
  __shared__ unsigned short ldsP[4][16 * PSTRIDE];
  int tid = threadIdx.x;
  int w = tid >> 6, lane = tid & 63;
  int m = lane & 15, quad = lane >> 4;
  int h = blockIdx.y;
  int q0 = (blockIdx.x * 4 + w) * 16;
  unsigned short* P = ldsP[w];
  int tok = q0 + m;                       // this lane's q-row
  int b = ids[tok];
  int st = offs[b], en = offs[b + 1];
  int kmin = st, kmax = en, stM = st, enm = en;
#pragma unroll
  for (int d = 1; d <= 8; d <<= 1) {      // st/en depend only on m -> 16-wide reduce
    kmin = min(kmin, __shfl_xor(kmin, d));
    kmax = max(kmax, __shfl_xor(kmax, d));
    stM  = max(stM,  __shfl_xor(stM,  d));
    enm  = min(enm,  __shfl_xor(enm,  d));
  }
  bf16x8 qf = ld8(Qb + (size_t)(h * N_TOK + tok) * HD + quad * 8);
  f32x4 o0 = {}, o1 = {};
  float mr = -3e38f, lr = 0.f;
  const float SC = 0.17677669529663687f * 1.4426950408889634f;  // 1/sqrt(32)*log2(e)

  for (int k0 = (kmin & ~63); k0 < kmax; k0 += 64) {  // N_TOK % 64 == 0: loads in-bounds
    f32x4 s[4];
#pragma unroll
    for (int i = 0; i < 4; ++i) {
      bf16x8 kf = ld8(Kb + (size_t)(h * N_TOK + k0 + 16 * i + m) * HD + quad * 8);
      f32x4 z = {};
      s[i] = __builtin_amdgcn_mfma_f32_16x16x32_bf16(kf, qf, z, 0, 0, 0);
    }
    float vm[16];
    if (k0 >= stM && k0 + 64 <= enm) {    // wave-uniform interior fast path
#pragma unroll
      for (int i = 0; i < 4; ++i)
#pragma unroll
        for (int r = 0; r < 4; ++r) vm[4 * i + r] = s[i][r] * SC;
    } else {
      int jb = k0 + quad * 4;
#pragma unroll
      for (int i = 0; i < 4; ++i)
#pragma unroll
        for (int r = 0; r < 4; ++r) {
          int j = jb + 16 * i + r;
          bool ok = (j >= st) && (j < en);
          vm[4 * i + r] = ok ? s[i][r] * SC : -3e38f;
        }
    }
    // max over this lane's 16 keys + cross-quad (all 64 keys of the chunk)
    float c0 = fmaxf(fmaxf(vm[0], vm[1]), fmaxf(vm[2], vm[3]));
    float c1 = fmaxf(fmaxf(vm[4], vm[5]), fmaxf(vm[6], vm[7]));
    float c2 = fmaxf(fmaxf(vm[8], vm[9]), fmaxf(vm[10], vm[11]));
    float c3 = fmaxf(fmaxf(vm[12], vm[13]), fmaxf(vm[14], vm[15]));
    float cm = fmaxf(fmaxf(c0, c1), fmaxf(c2, c3));
    cm = fmaxf(cm, __shfl_xor(cm, 16));
    cm = fmaxf(cm, __shfl_xor(cm, 32));
    float mn = fmaxf(mr, cm);
    float alpha = exp2f(mr - mn);
    float mnc = fmaxf(mn, -1e30f);        // exp2(-3e38 - mnc) == 0 even when mn==-3e38
    float sum = 0.f;
#pragma unroll
    for (int i = 0; i < 4; ++i) {
      float p0 = exp2f(vm[4 * i + 0] - mnc);
      float p1 = exp2f(vm[4 * i + 1] - mnc);
      float p2 = exp2f(vm[4 * i + 2] - mnc);
      float p3 = exp2f(vm[4 * i + 3] - mnc);
      sum += (p0 + p1) + (p2 + p3);
      uint2 pk;
      pk.x = (unsigned int)f2bf(p0) | ((unsigned int)f2bf(p1) << 16);
      pk.y = (unsigned int)f2bf(p2) | ((unsigned int)f2bf(p3) << 16);
      *(uint2*)(P + m * PSTRIDE + 16 * i + quad * 4) = pk;   // P^T[q=m][key=16i+quad*4+r]
    }
    sum += __shfl_xor(sum, 16);
    sum += __shfl_xor(sum, 32);
    lr = lr * alpha + sum;
    mr = mn;
    o0 *= alpha; o1 *= alpha;
#pragma unroll
    for (int c = 0; c < 2; ++c) {         // two 32-key sub-chunks
      bf16x8 pf  = ld8(P + m * PSTRIDE + 32 * c + quad * 8);           // B: P^T[q][k]
      bf16x8 vf0 = ld8(Vt + (size_t)(h * HD + m) * N_TOK + k0 + 32 * c + quad * 8);
      bf16x8 vf1 = ld8(Vt + (size_t)(h * HD + 16 + m) * N_TOK + k0 + 32 * c + quad * 8);
      o0 = __builtin_amdgcn_mfma_f32_16x16x32_bf16(vf0, pf, o0, 0, 0, 0);  // d 0..15
      o1 = __builtin_amdgcn_mfma_f32_16x16x32_bf16(vf1, pf, o1, 0, 0, 0);  // d 16..31
    }
  }
  float inv = 1.0f / lr;                  // every q-row has >=1 valid key
  ushort4 pk0, pk1;
  pk0.x = f2bf(o0[0] * inv); pk0.y = f2bf(o0[1] * inv);
  pk0.z = f2bf(o0[2] * inv); pk0.w = f2bf(o0[3] * inv);
  pk1.x = f2bf(o1[0] * inv); pk1.y = f2bf(o1[1] * inv);
  pk1.z = f2bf(o1[2] * inv); pk1.w = f2bf(o1[3] * inv);
  // O^T: col=q(lane&15)=this lane's tok; row=d=quad*4+r (+16 for o1)
  *(ushort4*)(attnb + (size_t)tok * E + h * HD + quad * 4) = pk0;
  *(ushort4*)(attnb + (size_t)tok * E + h * HD + 16 + quad * 4) = pk1;
}

// ---------------- K4: output projection ----------------
__global__ __launch_bounds__(256) void k_oproj(
    const unsigned short* __restrict__ attnb, const unsigned short* __restrict__ owb,
    const float* __restrict__ ob, float* __restrict__ out) {
  int tid = threadIdx.x;
  int w = tid >> 6, lane = tid & 63, m = lane & 15, quad = lane >> 4;
  int tok0 = blockIdx.x * 64, col0 = blockIdx.y * 64;
  f32x4 acc[4] = {};
  int arow = tok0 + 16 * w + m;
  for (int kc = 0; kc < 8; ++kc) {
    int ko = kc * 32 + quad * 8;
    bf16x8 a = ld8(attnb + (size_t)arow * E + ko);
#pragma unroll
    for (int t = 0; t < 4; ++t) {
      bf16x8 b = ld8(owb + (size_t)(col0 + 16 * t + m) * E + ko);
      acc[t] = __builtin_amdgcn_mfma_f32_16x16x32_bf16(a, b, acc[t], 0, 0, 0);
    }
  }
#pragma unroll
  for (int t = 0; t < 4; ++t) {
    int j = col0 + 16 * t + m;
    float bias = ob[j];
#pragma unroll
    for (int r = 0; r < 4; ++r) {
      int tok = tok0 + 16 * w + quad * 4 + r;
      out[(size_t)tok * E + j] = acc[t][r] + bias;
    }
  }
}

extern "C" void kernel_launch(void* const* d_in, const int* in_sizes, int n_in,
                              void* d_out, int out_size, void* d_ws, size_t ws_size,
                              hipStream_t stream) {
  const float* x   = (const float*)d_in[0];
  const int*   ids = (const int*)d_in[1];
  const float* qw  = (const float*)d_in[2];
  const float* qb  = (const float*)d_in[3];
  const float* ow  = (const float*)d_in[4];
  const float* ob  = (const float*)d_in[5];
  float* out = (float*)d_out;

  char* p = (char*)d_ws;
  auto alloc = [&](size_t bytes) {
    char* r = p;
    p += (bytes + 255) & ~(size_t)255;
    return r;
  };
  int* offs = (int*)alloc(32 * sizeof(int));
  unsigned short* xhi = (unsigned short*)alloc((size_t)N_TOK * E * 2);
  unsigned short* xlo = (unsigned short*)alloc((size_t)N_TOK * E * 2);
  unsigned short* whi = (unsigned short*)alloc((size_t)3 * E * E * 2);
  unsigned short* wlo = (unsigned short*)alloc((size_t)3 * E * E * 2);
  unsigned short* owb = (unsigned short*)alloc((size_t)E * E * 2);
  unsigned short* Qb  = (unsigned short*)alloc((size_t)N_TOK * E * 2);
  unsigned short* Kb  = (unsigned short*)alloc((size_t)N_TOK * E * 2);
  unsigned short* Vt  = (unsigned short*)alloc((size_t)N_TOK * E * 2);
  unsigned short* att = (unsigned short*)alloc((size_t)N_TOK * E * 2);

  k_offsets<<<dim3(1), dim3(64), 0, stream>>>(ids, offs);
  k_split<<<dim3(2048), dim3(256), 0, stream>>>(x, qw, ow, xhi, xlo, whi, wlo, owb);
  k_qkv<<<dim3(N_TOK / 64, 12), dim3(256), 0, stream>>>(xhi, xlo, whi, wlo, qb, Qb, Kb, Vt);
  k_attn<<<dim3(N_TOK / 64, H), dim3(256), 0, stream>>>(ids, offs, Qb, Kb, Vt, att);
  k_oproj<<<dim3(N_TOK / 64, E / 64), dim3(256), 0, stream>>>(att, owb, ob, out);
}

// Round 3
// 191.017 us; speedup vs baseline: 1.6114x; 1.3080x over previous
//
#include <hip/hip_runtime.h>
#include <stdint.h>

// Ragged-batch MHA: N=11136 tokens, 16 segments (contiguous, batch_ids sorted),
// E=256, H=8, hd=32. Pipeline:
//   K0: segment offsets via binary search (17 values)
//   K2: qkv = x @ qkv_w^T + b. fp32 inputs split to hi+lo bf16 IN-KERNEL
//       (weights split during LDS staging, x split in-register), 3-MFMA per frag.
//       Scatter to Q[h][n][d], K[h][n][d], Vt[h][d][n].
//   K3: flash attention, transposed-score formulation (S^T = K Q^T), 4 waves/block
//   K4: out = attn @ o_w^T + o_b, o_w converted fp32->bf16 during LDS staging.

#define N_TOK 11136
#define E 256
#define H 8
#define HD 32

typedef __attribute__((ext_vector_type(8))) __bf16 bf16x8;
typedef __attribute__((ext_vector_type(8))) unsigned short u16x8;
typedef __attribute__((ext_vector_type(4))) float f32x4;

__device__ __forceinline__ unsigned short f2bf(float f) {
  unsigned int u = __float_as_uint(f);
  u = (u + 0x7FFFu + ((u >> 16) & 1u)) >> 16;   // RNE
  return (unsigned short)u;
}
__device__ __forceinline__ float bf2f(unsigned short s) {
  return __uint_as_float(((unsigned int)s) << 16);
}
__device__ __forceinline__ bf16x8 ld8(const unsigned short* p) {
  return *(const bf16x8*)p;
}

// ---------------- K0: segment offsets ----------------
__global__ void k_offsets(const int* __restrict__ ids, int* __restrict__ offs) {
  int b = threadIdx.x;
  if (b > 16) return;
  int lo = 0, hi = N_TOK;
  while (lo < hi) { int mid = (lo + hi) >> 1; if (ids[mid] < b) lo = mid + 1; else hi = mid; }
  offs[b] = lo;   // lower_bound(b); offs[0]=0, offs[16]=N
}

// ---------------- K2: qkv projection ----------------
// Tile M=192 (4 waves x 3 m-tiles), N=48 (3 t-tiles), K=256 (whole).
// Weight tile split hi/lo into LDS once per block; x split in-register per kc.
#define QK_BSTRIDE 264   // 256 + 8 pad: lane bank = 4*(m+quad)%32 -> even spread
__global__ __launch_bounds__(256, 2) void k_qkv(
    const float* __restrict__ x, const float* __restrict__ qw,
    const float* __restrict__ qkv_b,
    unsigned short* __restrict__ Qb, unsigned short* __restrict__ Kb,
    unsigned short* __restrict__ Vt) {
  __shared__ unsigned short Bhi[48 * QK_BSTRIDE];
  __shared__ unsigned short Blo[48 * QK_BSTRIDE];
  int tid = threadIdx.x;
  int w = tid >> 6, lane = tid & 63, m = lane & 15, quad = lane >> 4;
  int col0 = blockIdx.y * 48;

  // ---- stage + split weight tile: 48 rows x 256 cols fp32 -> hi/lo bf16 LDS ----
  {
    const float4* qw4 = (const float4*)(qw + (size_t)col0 * E);
#pragma unroll
    for (int i = 0; i < 12; ++i) {        // 48*64 float4s / 256 threads
      int flat = i * 256 + tid;
      float4 v = qw4[flat];
      int row = flat >> 6, kq = flat & 63;
      ushort4 hv, lv;
      hv.x = f2bf(v.x); lv.x = f2bf(v.x - bf2f(hv.x));
      hv.y = f2bf(v.y); lv.y = f2bf(v.y - bf2f(hv.y));
      hv.z = f2bf(v.z); lv.z = f2bf(v.z - bf2f(hv.z));
      hv.w = f2bf(v.w); lv.w = f2bf(v.w - bf2f(hv.w));
      *(ushort4*)(Bhi + row * QK_BSTRIDE + kq * 4) = hv;
      *(ushort4*)(Blo + row * QK_BSTRIDE + kq * 4) = lv;
    }
  }
  __syncthreads();

  int base = blockIdx.x * 192 + w * 48;   // 58*192 == 11136 exactly
  f32x4 acc[3][3] = {};
  for (int kc = 0; kc < 8; ++kc) {
    int ko = kc * 32 + quad * 8;
    bf16x8 ah[3], al[3];
#pragma unroll
    for (int mt = 0; mt < 3; ++mt) {
      const float* ap = x + (size_t)(base + mt * 16 + m) * E + ko;
      float4 u0 = *(const float4*)ap;
      float4 u1 = *(const float4*)(ap + 4);
      float vv[8] = {u0.x, u0.y, u0.z, u0.w, u1.x, u1.y, u1.z, u1.w};
      u16x8 hr, lr_;
#pragma unroll
      for (int i = 0; i < 8; ++i) {
        unsigned short hh = f2bf(vv[i]);
        hr[i] = hh;
        lr_[i] = f2bf(vv[i] - bf2f(hh));
      }
      ah[mt] = __builtin_bit_cast(bf16x8, hr);
      al[mt] = __builtin_bit_cast(bf16x8, lr_);
    }
#pragma unroll
    for (int t = 0; t < 3; ++t) {
      bf16x8 bh = ld8(Bhi + (16 * t + m) * QK_BSTRIDE + ko);
      bf16x8 bl = ld8(Blo + (16 * t + m) * QK_BSTRIDE + ko);
#pragma unroll
      for (int mt = 0; mt < 3; ++mt) {
        acc[mt][t] = __builtin_amdgcn_mfma_f32_16x16x32_bf16(ah[mt], bh, acc[mt][t], 0, 0, 0);
        acc[mt][t] = __builtin_amdgcn_mfma_f32_16x16x32_bf16(ah[mt], bl, acc[mt][t], 0, 0, 0);
        acc[mt][t] = __builtin_amdgcn_mfma_f32_16x16x32_bf16(al[mt], bh, acc[mt][t], 0, 0, 0);
      }
    }
  }
  // epilogue: C layout col=lane&15, row=quad*4+reg. 16-col groups (start mult of 16)
  // never straddle q/k/v 32-boundaries -> wave-uniform routing per t.
#pragma unroll
  for (int t = 0; t < 3; ++t) {
    int j = col0 + 16 * t + m;
    int hd = j / 96;
    int rr = j - hd * 96;
    float bias = qkv_b[j];
#pragma unroll
    for (int mt = 0; mt < 3; ++mt) {
      int tokb = base + mt * 16 + quad * 4;
      if (rr < 64) {
        unsigned short* dst = (rr < 32) ? (Qb + (size_t)hd * N_TOK * HD + rr)
                                        : (Kb + (size_t)hd * N_TOK * HD + (rr - 32));
#pragma unroll
        for (int r = 0; r < 4; ++r)
          dst[(size_t)(tokb + r) * HD] = f2bf(acc[mt][t][r] + bias);
      } else {
        int d = rr - 64;
        ushort4 pk;
        pk.x = f2bf(acc[mt][t][0] + bias); pk.y = f2bf(acc[mt][t][1] + bias);
        pk.z = f2bf(acc[mt][t][2] + bias); pk.w = f2bf(acc[mt][t][3] + bias);
        *(ushort4*)(Vt + (size_t)(hd * HD + d) * N_TOK + tokb) = pk;
      }
    }
  }
}

// ---------------- K3: flash attention, transposed scores ----------------
// S^T = K·Q^T via mfma(A=K_frag, B=Q_frag): row=key (quad*4+r), col=q (lane&15).
// Each lane owns ONE q-row -> per-lane scalar m/l/alpha, 2-shuffle reductions.
// O^T = V^T·P^T via mfma(A=V_frag, B=P^T_frag): row=d, col=q.
// 4 waves/block, one 16-row q-tile per wave, no __syncthreads (per-wave LDS).
#define PSTRIDE 72
__global__ __launch_bounds__(256) void k_attn(
    const int* __restrict__ ids, const int* __restrict__ offs,
    const unsigned short* __restrict__ Qb, const unsigned short* __restrict__ Kb,
    const unsigned short* __restrict__ Vt,
    unsigned short* __restrict__ attnb) {
  __shared__ unsigned short ldsP[4][16 * PSTRIDE];
  int tid = threadIdx.x;
  int w = tid >> 6, lane = tid & 63;
  int m = lane & 15, quad = lane >> 4;
  int h = blockIdx.y;
  int q0 = (blockIdx.x * 4 + w) * 16;
  unsigned short* P = ldsP[w];
  int tok = q0 + m;                       // this lane's q-row
  int b = ids[tok];
  int st = offs[b], en = offs[b + 1];
  int kmin = st, kmax = en, stM = st, enm = en;
#pragma unroll
  for (int d = 1; d <= 8; d <<= 1) {      // st/en depend only on m -> 16-wide reduce
    kmin = min(kmin, __shfl_xor(kmin, d));
    kmax = max(kmax, __shfl_xor(kmax, d));
    stM  = max(stM,  __shfl_xor(stM,  d));
    enm  = min(enm,  __shfl_xor(enm,  d));
  }
  bf16x8 qf = ld8(Qb + (size_t)(h * N_TOK + tok) * HD + quad * 8);
  f32x4 o0 = {}, o1 = {};
  float mr = -3e38f, lr = 0.f;
  const float SC = 0.17677669529663687f * 1.4426950408889634f;  // 1/sqrt(32)*log2(e)

  for (int k0 = (kmin & ~63); k0 < kmax; k0 += 64) {  // N_TOK % 64 == 0: loads in-bounds
    f32x4 s[4];
#pragma unroll
    for (int i = 0; i < 4; ++i) {
      bf16x8 kf = ld8(Kb + (size_t)(h * N_TOK + k0 + 16 * i + m) * HD + quad * 8);
      f32x4 z = {};
      s[i] = __builtin_amdgcn_mfma_f32_16x16x32_bf16(kf, qf, z, 0, 0, 0);
    }
    float vm[16];
    if (k0 >= stM && k0 + 64 <= enm) {    // wave-uniform interior fast path
#pragma unroll
      for (int i = 0; i < 4; ++i)
#pragma unroll
        for (int r = 0; r < 4; ++r) vm[4 * i + r] = s[i][r] * SC;
    } else {
      int jb = k0 + quad * 4;
#pragma unroll
      for (int i = 0; i < 4; ++i)
#pragma unroll
        for (int r = 0; r < 4; ++r) {
          int j = jb + 16 * i + r;
          bool ok = (j >= st) && (j < en);
          vm[4 * i + r] = ok ? s[i][r] * SC : -3e38f;
        }
    }
    // max over this lane's 16 keys + cross-quad (all 64 keys of the chunk)
    float c0 = fmaxf(fmaxf(vm[0], vm[1]), fmaxf(vm[2], vm[3]));
    float c1 = fmaxf(fmaxf(vm[4], vm[5]), fmaxf(vm[6], vm[7]));
    float c2 = fmaxf(fmaxf(vm[8], vm[9]), fmaxf(vm[10], vm[11]));
    float c3 = fmaxf(fmaxf(vm[12], vm[13]), fmaxf(vm[14], vm[15]));
    float cm = fmaxf(fmaxf(c0, c1), fmaxf(c2, c3));
    cm = fmaxf(cm, __shfl_xor(cm, 16));
    cm = fmaxf(cm, __shfl_xor(cm, 32));
    float mn = fmaxf(mr, cm);
    float alpha = exp2f(mr - mn);
    float mnc = fmaxf(mn, -1e30f);        // exp2(-3e38 - mnc) == 0 even when mn==-3e38
    float sum = 0.f;
#pragma unroll
    for (int i = 0; i < 4; ++i) {
      float p0 = exp2f(vm[4 * i + 0] - mnc);
      float p1 = exp2f(vm[4 * i + 1] - mnc);
      float p2 = exp2f(vm[4 * i + 2] - mnc);
      float p3 = exp2f(vm[4 * i + 3] - mnc);
      sum += (p0 + p1) + (p2 + p3);
      uint2 pk;
      pk.x = (unsigned int)f2bf(p0) | ((unsigned int)f2bf(p1) << 16);
      pk.y = (unsigned int)f2bf(p2) | ((unsigned int)f2bf(p3) << 16);
      *(uint2*)(P + m * PSTRIDE + 16 * i + quad * 4) = pk;   // P^T[q=m][key=16i+quad*4+r]
    }
    sum += __shfl_xor(sum, 16);
    sum += __shfl_xor(sum, 32);
    lr = lr * alpha + sum;
    mr = mn;
    o0 *= alpha; o1 *= alpha;
#pragma unroll
    for (int c = 0; c < 2; ++c) {         // two 32-key sub-chunks
      bf16x8 pf  = ld8(P + m * PSTRIDE + 32 * c + quad * 8);           // B: P^T[q][k]
      bf16x8 vf0 = ld8(Vt + (size_t)(h * HD + m) * N_TOK + k0 + 32 * c + quad * 8);
      bf16x8 vf1 = ld8(Vt + (size_t)(h * HD + 16 + m) * N_TOK + k0 + 32 * c + quad * 8);
      o0 = __builtin_amdgcn_mfma_f32_16x16x32_bf16(vf0, pf, o0, 0, 0, 0);  // d 0..15
      o1 = __builtin_amdgcn_mfma_f32_16x16x32_bf16(vf1, pf, o1, 0, 0, 0);  // d 16..31
    }
  }
  float inv = 1.0f / lr;                  // every q-row has >=1 valid key
  ushort4 pk0, pk1;
  pk0.x = f2bf(o0[0] * inv); pk0.y = f2bf(o0[1] * inv);
  pk0.z = f2bf(o0[2] * inv); pk0.w = f2bf(o0[3] * inv);
  pk1.x = f2bf(o1[0] * inv); pk1.y = f2bf(o1[1] * inv);
  pk1.z = f2bf(o1[2] * inv); pk1.w = f2bf(o1[3] * inv);
  // O^T: col=q(lane&15)=this lane's tok; row=d=quad*4+r (+16 for o1)
  *(ushort4*)(attnb + (size_t)tok * E + h * HD + quad * 4) = pk0;
  *(ushort4*)(attnb + (size_t)tok * E + h * HD + 16 + quad * 4) = pk1;
}

// ---------------- K4: output projection ----------------
// Tile M=64 (4 waves x 1 m-tile), N=64 (4 t-tiles), K=256 whole.
// o_w tile converted fp32->bf16 into LDS once per block.
__global__ __launch_bounds__(256, 2) void k_oproj(
    const unsigned short* __restrict__ attnb, const float* __restrict__ ow,
    const float* __restrict__ ob, float* __restrict__ out) {
  __shared__ unsigned short Bo[64 * QK_BSTRIDE];
  int tid = threadIdx.x;
  int w = tid >> 6, lane = tid & 63, m = lane & 15, quad = lane >> 4;
  int tok0 = blockIdx.x * 64, col0 = blockIdx.y * 64;
  {
    const float4* ow4 = (const float4*)(ow + (size_t)col0 * E);
#pragma unroll
    for (int i = 0; i < 16; ++i) {        // 64*64 float4s / 256 threads
      int flat = i * 256 + tid;
      float4 v = ow4[flat];
      int row = flat >> 6, kq = flat & 63;
      ushort4 hv;
      hv.x = f2bf(v.x); hv.y = f2bf(v.y); hv.z = f2bf(v.z); hv.w = f2bf(v.w);
      *(ushort4*)(Bo + row * QK_BSTRIDE + kq * 4) = hv;
    }
  }
  __syncthreads();
  f32x4 acc[4] = {};
  int arow = tok0 + 16 * w + m;
  for (int kc = 0; kc < 8; ++kc) {
    int ko = kc * 32 + quad * 8;
    bf16x8 a = ld8(attnb + (size_t)arow * E + ko);
#pragma unroll
    for (int t = 0; t < 4; ++t) {
      bf16x8 b = ld8(Bo + (16 * t + m) * QK_BSTRIDE + ko);
      acc[t] = __builtin_amdgcn_mfma_f32_16x16x32_bf16(a, b, acc[t], 0, 0, 0);
    }
  }
#pragma unroll
  for (int t = 0; t < 4; ++t) {
    int j = col0 + 16 * t + m;
    float bias = ob[j];
#pragma unroll
    for (int r = 0; r < 4; ++r) {
      int tok = tok0 + 16 * w + quad * 4 + r;
      out[(size_t)tok * E + j] = acc[t][r] + bias;
    }
  }
}

extern "C" void kernel_launch(void* const* d_in, const int* in_sizes, int n_in,
                              void* d_out, int out_size, void* d_ws, size_t ws_size,
                              hipStream_t stream) {
  const float* x   = (const float*)d_in[0];
  const int*   ids = (const int*)d_in[1];
  const float* qw  = (const float*)d_in[2];
  const float* qb  = (const float*)d_in[3];
  const float* ow  = (const float*)d_in[4];
  const float* ob  = (const float*)d_in[5];
  float* out = (float*)d_out;

  char* p = (char*)d_ws;
  auto alloc = [&](size_t bytes) {
    char* r = p;
    p += (bytes + 255) & ~(size_t)255;
    return r;
  };
  int* offs = (int*)alloc(32 * sizeof(int));
  unsigned short* Qb  = (unsigned short*)alloc((size_t)N_TOK * E * 2);
  unsigned short* Kb  = (unsigned short*)alloc((size_t)N_TOK * E * 2);
  unsigned short* Vt  = (unsigned short*)alloc((size_t)N_TOK * E * 2);
  unsigned short* att = (unsigned short*)alloc((size_t)N_TOK * E * 2);

  k_offsets<<<dim3(1), dim3(64), 0, stream>>>(ids, offs);
  k_qkv<<<dim3(N_TOK / 192, 16), dim3(256), 0, stream>>>(x, qw, qb, Qb, Kb, Vt);
  k_attn<<<dim3(N_TOK / 64, H), dim3(256), 0, stream>>>(ids, offs, Qb, Kb, Vt, att);
  k_oproj<<<dim3(N_TOK / 64, E / 64), dim3(256), 0, stream>>>(att, ow, ob, out);
}